// Round 1
// baseline (700.559 us; speedup 1.0000x reference)
//
#include <hip/hip_runtime.h>

#define NTH 180
#define NPH 360
#define BATCH 1024

// clip(log(x), -100) in log2 domain: -100/ln2
#define LOG2_CLIP (-144.26950408889634f)
#define LN2F 0.6931471805599453f

__global__ void zero_acc_kernel(double* acc) {
    if (threadIdx.x == 0) { acc[0] = 0.0; acc[1] = 0.0; }
}

// Dense term: sum over ALL elements (both channels) of -clip(log1p(-p), -100).
// Accumulate log2(1-p) in f32 per thread, scale by -ln2 at block level.
__global__ __launch_bounds__(256) void dense_sum_kernel(
    const float* __restrict__ probs, long long n4, double* __restrict__ acc) {
    const float4* __restrict__ p4 = (const float4*)probs;
    long long idx = (long long)blockIdx.x * blockDim.x + threadIdx.x;
    long long stride = (long long)gridDim.x * blockDim.x;
    float s = 0.0f;
    for (long long i = idx; i < n4; i += stride) {
        float4 v = p4[i];
        s += fmaxf(__log2f(1.0f - v.x), LOG2_CLIP);
        s += fmaxf(__log2f(1.0f - v.y), LOG2_CLIP);
        s += fmaxf(__log2f(1.0f - v.z), LOG2_CLIP);
        s += fmaxf(__log2f(1.0f - v.w), LOG2_CLIP);
    }
    // wave (64-lane) reduce
    #pragma unroll
    for (int off = 32; off > 0; off >>= 1) s += __shfl_down(s, off);
    __shared__ float wsum[4];
    int lane = threadIdx.x & 63, wid = threadIdx.x >> 6;
    if (lane == 0) wsum[wid] = s;
    __syncthreads();
    if (threadIdx.x == 0) {
        float bs = wsum[0] + wsum[1] + wsum[2] + wsum[3];
        unsafeAtomicAdd(acc, (double)(-LN2F * bs));  // -ln2 * Σlog2(1-p) = Σ(-lq)
    }
}

// Sparse term: per (b, channel) sample, Σ_{i,j} y[i,j] * (lq - lp) with
// y = exp(-((i-t)^2+(j-p)^2)/2) / (Zθ*Zφ), window radius 12 (exact to 5e-32).
__global__ __launch_bounds__(64) void label_term_kernel(
    const float* __restrict__ probs, const float* __restrict__ gt_u,
    const float* __restrict__ gt_r, double* __restrict__ acc) {
    int bc = blockIdx.x;            // 0..2047
    int b = bc >> 1;
    int c = bc & 1;
    const float* g = (c == 0) ? gt_u : gt_r;
    float gx = g[b * 3 + 0], gy = g[b * 3 + 1], gz = g[b * 3 + 2];

    float theta = acosf(fminf(fmaxf(gz, -1.0f), 1.0f));
    float phi = atan2f(gy, gx);
    if (phi < 0.0f) phi += 6.283185307179586f;
    int t = (int)(theta / 3.14159265358979323846f * (float)NTH);
    t = min(max(t, 0), NTH - 1);
    int pb = (int)(phi / 6.283185307179586f * (float)NPH);
    pb = min(max(pb, 0), NPH - 1);

    const int R = 12;
    int i0 = max(0, t - R), i1 = min(NTH - 1, t + R);
    int j0 = max(0, pb - R), j1 = min(NPH - 1, pb + R);

    // Separable normalizer over the valid grid (mask at ±90/±180 never binds: R=12)
    float zt = 0.0f, zp = 0.0f;
    for (int i = i0; i <= i1; ++i) { float d = (float)(i - t);  zt += __expf(-0.5f * d * d); }
    for (int j = j0; j <= j1; ++j) { float d = (float)(j - pb); zp += __expf(-0.5f * d * d); }
    float invZ = 1.0f / (zt * zp);

    const float* __restrict__ P = probs + ((long long)b * 2 + c) * (NTH * NPH);
    int nj = j1 - j0 + 1;
    int npts = (i1 - i0 + 1) * nj;
    float s = 0.0f;
    for (int k = threadIdx.x; k < npts; k += 64) {
        int i = i0 + k / nj;
        int j = j0 + k % nj;
        float di = (float)(i - t), dj = (float)(j - pb);
        float w = __expf(-0.5f * (di * di + dj * dj));
        float pv = P[i * NPH + j];
        float lp = fmaxf(__logf(pv), -100.0f);
        float lq = fmaxf(__logf(1.0f - pv), -100.0f);
        s += w * (lq - lp);
    }
    #pragma unroll
    for (int off = 32; off > 0; off >>= 1) s += __shfl_down(s, off);
    if (threadIdx.x == 0) unsafeAtomicAdd(acc + 1, (double)(s * invZ));
}

__global__ void finalize_kernel(const double* __restrict__ acc, float* __restrict__ out) {
    if (threadIdx.x == 0) {
        double denom = (double)BATCH * (double)NTH * (double)NPH;  // per-channel mean denom
        out[0] = (float)((acc[0] + acc[1]) / denom);               // LOSS_WEIGHT = 1
    }
}

extern "C" void kernel_launch(void* const* d_in, const int* in_sizes, int n_in,
                              void* d_out, int out_size, void* d_ws, size_t ws_size,
                              hipStream_t stream) {
    const float* probs = (const float*)d_in[0];
    const float* gt_u  = (const float*)d_in[1];
    const float* gt_r  = (const float*)d_in[2];
    float* out = (float*)d_out;
    double* acc = (double*)d_ws;

    long long n = (long long)in_sizes[0];      // 1024*2*180*360 = 132,710,400
    long long n4 = n / 4;

    zero_acc_kernel<<<1, 64, 0, stream>>>(acc);
    dense_sum_kernel<<<2048, 256, 0, stream>>>(probs, n4, acc);
    label_term_kernel<<<2048, 64, 0, stream>>>(probs, gt_u, gt_r, acc);
    finalize_kernel<<<1, 64, 0, stream>>>(acc, out);
}

// Round 2
// 674.848 us; speedup vs baseline: 1.0381x; 1.0381x over previous
//
#include <hip/hip_runtime.h>

#define NTH 180
#define NPH 360
#define BATCH 1024
#define NBLK 2048            // one block per (b, channel); also the dense grid
#define NTHREADS 256

// clip(log(x), -100) in log2 domain: -100/ln2
#define LOG2_CLIP (-144.26950408889634f)
#define LN2F 0.6931471805599453f

// n = 1024*2*180*360 = 132,710,400 floats; n4 = 33,177,600 float4
// threads = 2048*256 = 524,288; 63 full iters = 33,030,144; tail = 147,456
#define N4_MAIN_ITERS 63
#define N4_TAIL_BASE 33030144
#define N4_TAIL 147456

// Phase A: dense sum of -clip(log1p(-p),-100) over all elements (f32 partial/block)
// Phase B: per-(b,c) Gaussian-label window term Σ y*(lq-lp) (exact to ~5e-32 at R=12)
__global__ __launch_bounds__(NTHREADS) void fused_kernel(
    const float* __restrict__ probs, const float* __restrict__ gt_u,
    const float* __restrict__ gt_r, float2* __restrict__ partial) {
    const float4* __restrict__ p4 = (const float4*)probs;
    int idx = blockIdx.x * NTHREADS + threadIdx.x;
    const int stride = NBLK * NTHREADS;

    // ---- Phase A: dense streaming reduction (accumulate log2(1-p)) ----
    float sd = 0.0f;
    #pragma unroll 4
    for (int it = 0; it < N4_MAIN_ITERS; ++it) {
        float4 v = p4[idx + it * stride];
        sd += fmaxf(__log2f(1.0f - v.x), LOG2_CLIP);
        sd += fmaxf(__log2f(1.0f - v.y), LOG2_CLIP);
        sd += fmaxf(__log2f(1.0f - v.z), LOG2_CLIP);
        sd += fmaxf(__log2f(1.0f - v.w), LOG2_CLIP);
    }
    if (idx < N4_TAIL) {
        float4 v = p4[N4_TAIL_BASE + idx];
        sd += fmaxf(__log2f(1.0f - v.x), LOG2_CLIP);
        sd += fmaxf(__log2f(1.0f - v.y), LOG2_CLIP);
        sd += fmaxf(__log2f(1.0f - v.z), LOG2_CLIP);
        sd += fmaxf(__log2f(1.0f - v.w), LOG2_CLIP);
    }

    // ---- Phase B: label window term for (b,c) = blockIdx ----
    int b = blockIdx.x >> 1;
    int c = blockIdx.x & 1;
    const float* g = (c == 0) ? gt_u : gt_r;
    float gx = g[b * 3 + 0], gy = g[b * 3 + 1], gz = g[b * 3 + 2];

    float theta = acosf(fminf(fmaxf(gz, -1.0f), 1.0f));
    float phi = atan2f(gy, gx);
    if (phi < 0.0f) phi += 6.283185307179586f;
    int t = (int)(theta * (1.0f / 3.14159265358979323846f) * (float)NTH);
    t = min(max(t, 0), NTH - 1);
    int pb = (int)(phi * (1.0f / 6.283185307179586f) * (float)NPH);
    pb = min(max(pb, 0), NPH - 1);

    const int R = 12;
    int i0 = max(0, t - R), i1 = min(NTH - 1, t + R);
    int j0 = max(0, pb - R), j1 = min(NPH - 1, pb + R);

    // Separable normalizer over the clipped window (ref mask never binds at R=12)
    float zt = 0.0f, zp = 0.0f;
    for (int i = i0; i <= i1; ++i) { float d = (float)(i - t);  zt += __expf(-0.5f * d * d); }
    for (int j = j0; j <= j1; ++j) { float d = (float)(j - pb); zp += __expf(-0.5f * d * d); }
    float invZ = 1.0f / (zt * zp);

    const float* __restrict__ P = probs + (blockIdx.x * (NTH * NPH));
    int nj = j1 - j0 + 1;
    int npts = (i1 - i0 + 1) * nj;
    float sl = 0.0f;
    for (int k = threadIdx.x; k < npts; k += NTHREADS) {
        int i = i0 + k / nj;
        int j = j0 + k % nj;
        float di = (float)(i - t), dj = (float)(j - pb);
        float w = __expf(-0.5f * (di * di + dj * dj));
        float pv = P[i * NPH + j];
        float lp = fmaxf(__logf(pv), -100.0f);
        float lq = fmaxf(__logf(1.0f - pv), -100.0f);
        sl += w * (lq - lp);
    }

    // ---- combined block reduction of (sd, sl) ----
    #pragma unroll
    for (int off = 32; off > 0; off >>= 1) {
        sd += __shfl_down(sd, off);
        sl += __shfl_down(sl, off);
    }
    __shared__ float wsd[4], wsl[4];
    int lane = threadIdx.x & 63, wid = threadIdx.x >> 6;
    if (lane == 0) { wsd[wid] = sd; wsl[wid] = sl; }
    __syncthreads();
    if (threadIdx.x == 0) {
        float bd = wsd[0] + wsd[1] + wsd[2] + wsd[3];
        float bl = wsl[0] + wsl[1] + wsl[2] + wsl[3];
        partial[blockIdx.x] = make_float2(-LN2F * bd, invZ * bl);
    }
}

// Reduce 2048 float2 partials in double, finalize the scalar loss.
__global__ __launch_bounds__(NTHREADS) void reduce_kernel(
    const float2* __restrict__ partial, float* __restrict__ out) {
    double s = 0.0;
    for (int i = threadIdx.x; i < NBLK; i += NTHREADS) {
        float2 v = partial[i];
        s += (double)v.x + (double)v.y;
    }
    #pragma unroll
    for (int off = 32; off > 0; off >>= 1) s += __shfl_down(s, off);
    __shared__ double wsum[4];
    int lane = threadIdx.x & 63, wid = threadIdx.x >> 6;
    if (lane == 0) wsum[wid] = s;
    __syncthreads();
    if (threadIdx.x == 0) {
        double tot = wsum[0] + wsum[1] + wsum[2] + wsum[3];
        double denom = (double)BATCH * (double)NTH * (double)NPH;
        out[0] = (float)(tot / denom);   // LOSS_WEIGHT = 1
    }
}

extern "C" void kernel_launch(void* const* d_in, const int* in_sizes, int n_in,
                              void* d_out, int out_size, void* d_ws, size_t ws_size,
                              hipStream_t stream) {
    const float* probs = (const float*)d_in[0];
    const float* gt_u  = (const float*)d_in[1];
    const float* gt_r  = (const float*)d_in[2];
    float* out = (float*)d_out;
    float2* partial = (float2*)d_ws;     // 2048 * 8 B = 16 KB, fully overwritten

    fused_kernel<<<NBLK, NTHREADS, 0, stream>>>(probs, gt_u, gt_r, partial);
    reduce_kernel<<<1, NTHREADS, 0, stream>>>(partial, out);
}